// Round 3
// baseline (484.398 us; speedup 1.0000x reference)
//
#include <hip/hip_runtime.h>
#include <math.h>

// Problem constants
#define T_SEQ 2048
#define D_MODEL 3072
#define NQ 16
#define NKV 8
#define HD 256
#define NHEADS_TOT 32
#define QKV_COLS 8192
#define SOFT_CAP 50.0f
#define WINDOW 1024
#define K_MASK -2.3819763e38f

typedef __attribute__((ext_vector_type(8))) short bf16x8;
typedef __attribute__((ext_vector_type(4))) float f32x4;

__device__ __forceinline__ unsigned short f2bf(float f) {
    union { float f; unsigned u; } v; v.f = f;
    unsigned r = (v.u + 0x7fff + ((v.u >> 16) & 1)) >> 16;
    return (unsigned short)r;
}
__device__ __forceinline__ float bf2f(unsigned short u) {
    union { unsigned u; float f; } v; v.u = ((unsigned)u) << 16;
    return v.f;
}

__device__ __forceinline__ void gl_lds16(const unsigned short* g, unsigned short* l) {
    __builtin_amdgcn_global_load_lds(
        (const __attribute__((address_space(1))) void*)g,
        (__attribute__((address_space(3))) void*)l, 16, 0, 0);
}

// ---------------- convert f32 -> bf16 (flat) ----------------
__global__ __launch_bounds__(256) void k_convert(const float* __restrict__ src,
                                                 unsigned short* __restrict__ dst, int n4) {
    int i = blockIdx.x * 256 + threadIdx.x;
    if (i >= n4) return;
    float4 v = ((const float4*)src)[i];
    ushort4 o;
    o.x = f2bf(v.x); o.y = f2bf(v.y); o.z = f2bf(v.z); o.w = f2bf(v.w);
    ((ushort4*)dst)[i] = o;
}

// ---------------- batched transpose+convert: (batch,R,C) f32 -> (batch,C,R) bf16 ----------------
__global__ __launch_bounds__(256) void k_transpose_bf16(const float* __restrict__ src,
                                                        unsigned short* __restrict__ dst,
                                                        int R, int C) {
    __shared__ float tile[32][33];
    int b = blockIdx.z;
    src += (size_t)b * R * C;
    dst += (size_t)b * R * C;
    int c0 = blockIdx.x * 32, r0 = blockIdx.y * 32;
    int tx = threadIdx.x, ty = threadIdx.y;   // 32 x 8
    #pragma unroll
    for (int i = ty; i < 32; i += 8)
        tile[i][tx] = src[(size_t)(r0 + i) * C + c0 + tx];
    __syncthreads();
    #pragma unroll
    for (int i = ty; i < 32; i += 8)
        dst[(size_t)(c0 + i) * R + r0 + tx] = f2bf(tile[tx][i]);
}

// ---------------- bf16 transpose: vh (8, T, H) -> vT (8, H, T) ----------------
__global__ __launch_bounds__(256) void k_transpose_v(const unsigned short* __restrict__ src,
                                                     unsigned short* __restrict__ dst) {
    __shared__ unsigned short tile[32][34];
    int kk = blockIdx.z;
    src += (size_t)kk * T_SEQ * HD;
    dst += (size_t)kk * HD * T_SEQ;
    int h0 = blockIdx.x * 32, t0 = blockIdx.y * 32;
    int tx = threadIdx.x, ty = threadIdx.y;   // 32 x 8
    #pragma unroll
    for (int i = ty; i < 32; i += 8)
        tile[i][tx] = src[(size_t)(t0 + i) * HD + h0 + tx];
    __syncthreads();
    #pragma unroll
    for (int i = ty; i < 32; i += 8)
        dst[(size_t)(h0 + i) * T_SEQ + t0 + tx] = tile[tx][i];
}

// ---------------- RoPE trig table: (T, 128) float2 {sin, cos} ----------------
__global__ __launch_bounds__(128) void k_trig(const int* __restrict__ spos,
                                              float2* __restrict__ tbl) {
    int t = blockIdx.x, hh = threadIdx.x;
    float fr = (float)hh * (1.0f / 128.0f);
    float ts = __expf(fr * 9.210340371976184f);   // 10000^fr
    float ang = (float)spos[t] / ts;
    float2 sc;
    sc.x = __sinf(ang);
    sc.y = __cosf(ang);
    tbl[(size_t)t * 128 + hh] = sc;
}

// ---------------- gemm1: 256x256 tile, BK=64, 8 waves, 8-phase counted-vmcnt schedule ----------
// C[M,N] = A * BT^T.  256 blocks (1/CU), 512 threads.  LDS 128 KiB double-buffered.
// R2: identical resubmit of R1 (bench infra failed; no data).  R1 fix: raw s_barrier is
// NOT a compiler scheduling fence -> scheduler sank the ds_reads past the barrier into
// the MFMA region, exposing full LDS latency per phase (R0: 0% gain from counted vmcnt).
// Each phase pinned per the m201 template + rule #18:
//   {ds_read frags; stage; sched_barrier(0); s_barrier; s_waitcnt lgkmcnt(0);
//    sched_barrier(0); setprio(1); 16 MFMA; setprio(0); sched_barrier(0); s_barrier}
// vmcnt(4) once per K-tile (counted, never drained mid-loop).
__global__ __launch_bounds__(512, 2) void k_gemm1(const unsigned short* __restrict__ A,
                                                  const unsigned short* __restrict__ BT,
                                                  unsigned short* __restrict__ C,
                                                  int M, int N, int Kd) {
    __shared__ unsigned short As[2 * 256 * 64];   // 64 KB (tile kt in buf kt&1)
    __shared__ unsigned short Bs[2 * 256 * 64];   // 64 KB

    const int tid = threadIdx.x;
    const int wave = tid >> 6, lane = tid & 63;
    const int col = lane & 15, quad = lane >> 4;
    const int wr = wave >> 2, wc = wave & 3;      // 2 x 4 wave grid; wave owns 128x64 of C

    int p = blockIdx.x;                 // 256 blocks, XCD-bijective swizzle (256 % 8 == 0)
    int xcd = p & 7, q = p >> 3;        // q in [0,32)
    int i_t = q & 7, jj = q >> 3;       // i_t in [0,8), jj in [0,4)
    const int m0 = i_t * 256, n0 = (jj * 8 + xcd) * 256;

    // staging geometry: per stage-call a wave fills 16 rows (2 x gl_lds16 of 8 rows);
    // chunk stored at (lane&7)^(row&7) -> proven 0-conflict read swizzle.
    const int lr3 = lane >> 3, lc7 = lane & 7;
    const int cxor = (lc7 ^ lr3) * 8;                       // row&7 == lr3 for all units
    const int rbA = (wave >> 2) * 128 + (wave & 3) * 16;    // + mh*64 : rows of A unit
    const int rbB = (wave >> 1) * 64 + (wave & 1) * 16;     // + nh*32 : rows of B unit

    const unsigned short* Ab = A + (size_t)m0 * Kd;
    const unsigned short* Bb = BT + (size_t)n0 * Kd;

#define SBAR() __builtin_amdgcn_sched_barrier(0)
#define PH_SYNC() do { SBAR(); __builtin_amdgcn_s_barrier();                              \
    asm volatile("s_waitcnt lgkmcnt(0)" ::: "memory"); SBAR(); } while (0)
#define PH_DONE() do { SBAR(); __builtin_amdgcn_s_barrier(); } while (0)

#define STG_A(bufp, mh, kt) do {                                                          \
    int rb_ = rbA + (mh) * 64;                                                            \
    gl_lds16(Ab + (size_t)(rb_ + lr3) * Kd + cxor + (kt) * 64, (bufp) + rb_ * 64);        \
    gl_lds16(Ab + (size_t)(rb_ + 8 + lr3) * Kd + cxor + (kt) * 64, (bufp) + (rb_ + 8) * 64); \
  } while (0)
#define STG_B(bufp, nh, kt) do {                                                          \
    int rb_ = rbB + (nh) * 32;                                                            \
    gl_lds16(Bb + (size_t)(rb_ + lr3) * Kd + cxor + (kt) * 64, (bufp) + rb_ * 64);        \
    gl_lds16(Bb + (size_t)(rb_ + 8 + lr3) * Kd + cxor + (kt) * 64, (bufp) + (rb_ + 8) * 64); \
  } while (0)

    f32x4 acc[8][4];
    #pragma unroll
    for (int i = 0; i < 8; i++)
        #pragma unroll
        for (int j2 = 0; j2 < 4; j2++)
            acc[i][j2] = (f32x4){0.f, 0.f, 0.f, 0.f};

    bf16x8 af[4][2];          // A frags of current mh-quadrant (reused across 2 phases)
    bf16x8 bf0[2][2], bf1[2][2];  // B frags nh=0 / nh=1 (both kept live across group)
    const int sw = col & 7;

#define LD_AF(bufp, mh) do {                                                              \
    _Pragma("unroll") for (int i = 0; i < 4; i++) {                                       \
      const unsigned short* rp_ = (bufp) + (wr * 128 + ((mh) * 4 + i) * 16 + col) * 64;   \
      af[i][0] = *(const bf16x8*)(rp_ + (quad ^ sw) * 8);                                 \
      af[i][1] = *(const bf16x8*)(rp_ + ((4 + quad) ^ sw) * 8);                           \
    } } while (0)
#define LD_BF(dst, bufp, nh) do {                                                         \
    _Pragma("unroll") for (int j2 = 0; j2 < 2; j2++) {                                    \
      const unsigned short* rp_ = (bufp) + (wc * 64 + ((nh) * 2 + j2) * 16 + col) * 64;   \
      dst[j2][0] = *(const bf16x8*)(rp_ + (quad ^ sw) * 8);                               \
      dst[j2][1] = *(const bf16x8*)(rp_ + ((4 + quad) ^ sw) * 8);                         \
    } } while (0)
#define MFMA16(mh, nh, BF) do {                                                           \
    __builtin_amdgcn_s_setprio(1);                                                        \
    _Pragma("unroll") for (int i = 0; i < 4; i++)                                         \
      _Pragma("unroll") for (int j2 = 0; j2 < 2; j2++) {                                  \
        acc[(mh)*4+i][(nh)*2+j2] = __builtin_amdgcn_mfma_f32_16x16x32_bf16(               \
            af[i][0], BF[j2][0], acc[(mh)*4+i][(nh)*2+j2], 0, 0, 0);                      \
        acc[(mh)*4+i][(nh)*2+j2] = __builtin_amdgcn_mfma_f32_16x16x32_bf16(               \
            af[i][1], BF[j2][1], acc[(mh)*4+i][(nh)*2+j2], 0, 0, 0);                      \
      }                                                                                   \
    __builtin_amdgcn_s_setprio(0);                                                        \
  } while (0)

// One K-tile group j: 4 phases.  CURx = buf[j&1], NXTx = buf[(j+1)&1].
// Stage calendar (race-free):
//   ph0: A-mh1(j+1)->NXT   ph1: B-nh1(j+1)->NXT
//   ph2: A-mh0(j+2)->CUR (rows disjoint from concurrent mh=1 reads)
//   ph3: B-nh0(j+2)->CUR (no concurrent LDS reads)
// ENDV=4 leaves exactly the ph2+ph3 stages (tile j+2) in flight; everything tile j+1
// needs is complete.  ENDV=0 only at group KT-2.
#define GROUP(CURA, CURB, NXTA, NXTB, S1, S2, ENDV, J) do {                               \
    /* phase 0: quadrant (mh0,nh0) */                                                     \
    LD_AF(CURA, 0); LD_BF(bf0, CURB, 0);                                                  \
    if (S1) STG_A(NXTA, 1, (J) + 1);                                                      \
    PH_SYNC();                                                                            \
    MFMA16(0, 0, bf0);                                                                    \
    PH_DONE();                                                                            \
    /* phase 1: quadrant (mh0,nh1) — reuse af */                                          \
    LD_BF(bf1, CURB, 1);                                                                  \
    if (S1) STG_B(NXTB, 1, (J) + 1);                                                      \
    PH_SYNC();                                                                            \
    MFMA16(0, 1, bf1);                                                                    \
    PH_DONE();                                                                            \
    /* phase 2: quadrant (mh1,nh0) — reuse bf0 */                                         \
    LD_AF(CURA, 1);                                                                       \
    if (S2) STG_A(CURA, 0, (J) + 2);                                                      \
    PH_SYNC();                                                                            \
    MFMA16(1, 0, bf0);                                                                    \
    PH_DONE();                                                                            \
    /* phase 3: quadrant (mh1,nh1) — reuse af & bf1 */                                    \
    if (S2) STG_B(CURB, 0, (J) + 2);                                                      \
    PH_SYNC();                                                                            \
    MFMA16(1, 1, bf1);                                                                    \
    SBAR();                                                                               \
    if ((ENDV) == 4)      asm volatile("s_waitcnt vmcnt(4)" ::: "memory");                \
    else if ((ENDV) == 0) asm volatile("s_waitcnt vmcnt(0)" ::: "memory");                \
    __builtin_amdgcn_s_barrier();                                                         \
  } while (0)

    unsigned short* A0 = As;          unsigned short* A1 = As + 16384;
    unsigned short* B0 = Bs;          unsigned short* B1 = Bs + 16384;

    // prologue: tile 0 complete + tile 1's mh0/nh0 units; vmcnt(4) -> tile 0 landed,
    // tile-1 units (4 loads) stay in flight.
    STG_A(A0, 0, 0); STG_B(B0, 0, 0);
    STG_A(A0, 1, 0); STG_B(B0, 1, 0);
    STG_A(A1, 0, 1); STG_B(B1, 0, 1);
    SBAR();
    asm volatile("s_waitcnt vmcnt(4)" ::: "memory");
    __builtin_amdgcn_s_barrier();

    // KT = Kd/64 = 48 K-tiles; pair-unrolled so all LDS offsets are compile-time.
    for (int kt = 0; kt < 46; kt += 2) {
        GROUP(A0, B0, A1, B1, 1, 1, 4, kt);
        GROUP(A1, B1, A0, B0, 1, 1, 4, kt + 1);
    }
    GROUP(A0, B0, A1, B1, 1, 0, 0, 46);   // stages tile 47's mh1/nh1 only; drain
    GROUP(A1, B1, A0, B0, 0, 0, -1, 47);  // pure compute, nothing outstanding

#undef GROUP
#undef MFMA16
#undef LD_BF
#undef LD_AF
#undef STG_B
#undef STG_A
#undef PH_DONE
#undef PH_SYNC
#undef SBAR

    #pragma unroll
    for (int i = 0; i < 8; i++) {
        int row = m0 + wr * 128 + i * 16 + quad * 4;
        #pragma unroll
        for (int j2 = 0; j2 < 4; j2++) {
            int c = n0 + wc * 64 + j2 * 16 + col;
            #pragma unroll
            for (int r = 0; r < 4; r++)
                C[(size_t)(row + r) * N + c] = f2bf(acc[i][j2][r]);
        }
    }
}

// ---------------- gemm2: 128x64 tile, BK=128 (32 barriers), 768 blocks, f32 out ----------------
// Ascending k-order per element -> bit-identical to BK=64 version.
__global__ __launch_bounds__(256) void k_gemm2(const unsigned short* __restrict__ A,
                                               const unsigned short* __restrict__ BT,
                                               float* __restrict__ C,
                                               int M, int N, int Kd) {
    __shared__ unsigned short As[128 * 128];  // 32 KB
    __shared__ unsigned short Bs[64 * 128];   // 16 KB
    const int tid = threadIdx.x;
    const int wave = tid >> 6, lane = tid & 63;
    const int col = lane & 15, quad = lane >> 4;

    int p = blockIdx.x;                    // 768 blocks
    int xcd = p & 7, q = p >> 3;           // q in [0,96)
    int i_t = q % 16, jj = q / 16;         // jj in [0,6)
    const int m0 = i_t * 128, n0 = (jj * 8 + xcd) * 64;

    const int lrow = lane >> 4, lchk = lane & 15;
    int soffA[8], soffB[4];
    #pragma unroll
    for (int s = 0; s < 8; s++) {
        int r = wave * 32 + s * 4 + lrow;
        soffA[s] = r * Kd + ((lchk ^ (r & 7)) * 8);
    }
    #pragma unroll
    for (int s = 0; s < 4; s++) {
        int r = wave * 16 + s * 4 + lrow;
        soffB[s] = r * Kd + ((lchk ^ (r & 7)) * 8);
    }
    const unsigned short* Ab = A + (size_t)m0 * Kd;
    const unsigned short* Bb = BT + (size_t)n0 * Kd;

    f32x4 acc[2][4];
    #pragma unroll
    for (int i = 0; i < 2; i++)
        #pragma unroll
        for (int j = 0; j < 4; j++)
            acc[i][j] = (f32x4){0.f, 0.f, 0.f, 0.f};

    const int sw = col & 7;

    for (int k0 = 0; k0 < Kd; k0 += 128) {
        #pragma unroll
        for (int s = 0; s < 8; s++)
            gl_lds16(Ab + soffA[s] + k0, &As[(wave * 32 + s * 4) * 128]);
        #pragma unroll
        for (int s = 0; s < 4; s++)
            gl_lds16(Bb + soffB[s] + k0, &Bs[(wave * 16 + s * 4) * 128]);
        __syncthreads();

        #pragma unroll
        for (int kk = 0; kk < 4; kk++) {
            const int chko = ((kk * 4 + quad) ^ sw) * 8;
            bf16x8 af[2], bfr[4];
            #pragma unroll
            for (int i = 0; i < 2; i++)
                af[i] = *(const bf16x8*)&As[(wave * 32 + i * 16 + col) * 128 + chko];
            #pragma unroll
            for (int j = 0; j < 4; j++)
                bfr[j] = *(const bf16x8*)&Bs[(j * 16 + col) * 128 + chko];
            #pragma unroll
            for (int i = 0; i < 2; i++)
                #pragma unroll
                for (int j = 0; j < 4; j++)
                    acc[i][j] = __builtin_amdgcn_mfma_f32_16x16x32_bf16(af[i], bfr[j], acc[i][j], 0, 0, 0);
        }
        __syncthreads();
    }

    #pragma unroll
    for (int i = 0; i < 2; i++) {
        int row = m0 + wave * 32 + i * 16 + quad * 4;
        #pragma unroll
        for (int j = 0; j < 4; j++) {
            int c = n0 + j * 16 + col;
            #pragma unroll
            for (int r = 0; r < 4; r++)
                C[(size_t)(row + r) * N + c] = acc[i][j][r];
        }
    }
}

// ---------------- RMS-norm (+scale) + RoPE: 4 slots per block ----------------
__global__ __launch_bounds__(256) void k_norm_rope(const unsigned short* __restrict__ qkv,
                                                   const float2* __restrict__ trig,
                                                   const float* __restrict__ qscale,
                                                   const float* __restrict__ kscale,
                                                   unsigned short* __restrict__ qh,
                                                   unsigned short* __restrict__ kh,
                                                   unsigned short* __restrict__ vh) {
    const int t = blockIdx.x, y = blockIdx.y, h = threadIdx.x;
    __shared__ float wsum[4][4];
    __shared__ float ybuf[3][256];

    float val[4];
    #pragma unroll
    for (int g = 0; g < 4; g++)
        val[g] = bf2f(qkv[(size_t)t * QKV_COLS + (y + g * 8) * HD + h]);

    float ssg[4];
    #pragma unroll
    for (int g = 0; g < 4; g++) {
        float ss = val[g] * val[g];
        #pragma unroll
        for (int m = 1; m < 64; m <<= 1) ss += __shfl_xor(ss, m, 64);
        ssg[g] = ss;
    }
    if ((h & 63) == 0) {
        #pragma unroll
        for (int g = 0; g < 4; g++) wsum[g][h >> 6] = ssg[g];
    }
    __syncthreads();

    float2 sc = trig[(size_t)t * 128 + (h & 127)];
    float qs = 1.0f + qscale[h], ks = 1.0f + kscale[h];

    float yv[4];
    #pragma unroll
    for (int g = 0; g < 4; g++) {
        float tot = wsum[g][0] + wsum[g][1] + wsum[g][2] + wsum[g][3];
        float yy = val[g] * rsqrtf(tot * (1.0f / 256.0f) + 1e-6f);
        if (g < 2) yy *= qs;
        else if (g == 2) yy *= ks;
        yv[g] = yy;
        if (g < 3) ybuf[g][h] = yy;
    }
    __syncthreads();

    #pragma unroll
    for (int g = 0; g < 3; g++) {
        float other = ybuf[g][(h < 128) ? (h + 128) : (h - 128)];
        float outv = (h < 128) ? (yv[g] * sc.y - other * sc.x)
                               : (yv[g] * sc.y + other * sc.x);
        int slot = y + g * 8;
        if (slot < 16)
            qh[((size_t)slot * T_SEQ + t) * HD + h] = f2bf(outv);
        else
            kh[((size_t)(slot - 16) * T_SEQ + t) * HD + h] = f2bf(outv);
    }
    vh[((size_t)y * T_SEQ + t) * HD + h] = f2bf(yv[3]);
}

// ---------------- flash attention (32-s-tile, R3-proven) ----------------
__global__ __launch_bounds__(256) void k_attn(const unsigned short* __restrict__ qh,
                                              const unsigned short* __restrict__ kh,
                                              const unsigned short* __restrict__ vT,
                                              unsigned short* __restrict__ enc) {
    __shared__ unsigned short Ks[32 * 256];
    __shared__ unsigned short Vs[256 * 32];
    __shared__ unsigned short Pl[4][16 * 40];

    const int tid = threadIdx.x;
    const int wave = tid >> 6, lane = tid & 63;
    const int col = lane & 15, quad = lane >> 4;
    const int kk = blockIdx.x;
    const int t0b = blockIdx.y * 32;
    const int headSel = wave & 1, rowSel = wave >> 1;
    const int n = kk * 2 + headSel;
    const int tw = t0b + rowSel * 16;

    const unsigned short* qp = qh + ((size_t)n * T_SEQ + tw) * HD;
    const unsigned short* kp = kh + (size_t)kk * T_SEQ * HD;
    const unsigned short* vp = vT + (size_t)kk * HD * T_SEQ;

    bf16x8 qf[8];
    #pragma unroll
    for (int c = 0; c < 8; c++)
        qf[c] = *(const bf16x8*)(qp + (size_t)col * HD + c * 32 + quad * 8);

    int preK[4], preV[4], ldsKo[4], ldsVo[4];
    #pragma unroll
    for (int i = 0; i < 4; i++) {
        int krow = 2 * (wave * 4 + i) + (lane >> 5);
        int kpos = lane & 31;
        preK[i] = krow * HD + ((kpos ^ (krow & 7)) * 8);
        ldsKo[i] = (wave * 4 + i) * 512;
        int vh2 = (wave * 4 + i) * 16 + (lane >> 2);
        int vpp = lane & 3;
        preV[i] = vh2 * T_SEQ + ((vpp ^ (vh2 & 3)) * 8);
        ldsVo[i] = (wave * 4 + i) * 512;
    }

    f32x4 o[16];
    #pragma unroll
    for (int h = 0; h < 16; h++) o[h] = (f32x4){0.f, 0.f, 0.f, 0.f};
    float lsum[4] = {0.f, 0.f, 0.f, 0.f};

    int s_begin = t0b - (WINDOW - 1);
    if (s_begin < 0) s_begin = 0;
    s_begin &= ~31;
    const int s_end = t0b + 32;

    for (int s0 = s_begin; s0 < s_end; s0 += 32) {
        #pragma unroll
        for (int i = 0; i < 4; i++)
            gl_lds16(kp + (size_t)s0 * HD + preK[i], &Ks[ldsKo[i]]);
        #pragma unroll
        for (int i = 0; i < 4; i++)
            gl_lds16(vp + (size_t)s0 + preV[i], &Vs[ldsVo[i]]);
        __syncthreads();

        f32x4 S0 = (f32x4){0.f, 0.f, 0.f, 0.f};
        f32x4 S1 = (f32x4){0.f, 0.f, 0.f, 0.f};
        #pragma unroll
        for (int c = 0; c < 8; c++) {
            bf16x8 kf = *(const bf16x8*)&Ks[(size_t)col * HD + (((c * 4 + quad) ^ (col & 7)) * 8)];
            S0 = __builtin_amdgcn_mfma_f32_16x16x32_bf16(qf[c], kf, S0, 0, 0, 0);
        }
        #pragma unroll
        for (int c = 0; c < 8; c++) {
            bf16x8 kf = *(const bf16x8*)&Ks[(size_t)(16 + col) * HD + (((c * 4 + quad) ^ (col & 7)) * 8)];
            S1 = __builtin_amdgcn_mfma_f32_16x16x32_bf16(qf[c], kf, S1, 0, 0, 0);
        }

        #pragma unroll
        for (int r = 0; r < 4; r++) {
            int t = tw + quad * 4 + r;
            int sA = s0 + col, sB = sA + 16;
            bool vA = (sA <= t) && (sA >= t - (WINDOW - 1));
            bool vB = (sB <= t) && (sB >= t - (WINDOW - 1));
            float eA = __expf(S0[r] * (2.0f / SOFT_CAP));
            float eB = __expf(S1[r] * (2.0f / SOFT_CAP));
            float rA = __builtin_amdgcn_rcpf(eA + 1.0f);
            float rB = __builtin_amdgcn_rcpf(eB + 1.0f);
            float pA = __expf(SOFT_CAP - 2.0f * SOFT_CAP * rA);
            float pB = __expf(SOFT_CAP - 2.0f * SOFT_CAP * rB);
            pA = vA ? pA : 0.0f;
            pB = vB ? pB : 0.0f;
            lsum[r] += pA + pB;
            Pl[wave][(quad * 4 + r) * 40 + col] = f2bf(pA);
            Pl[wave][(quad * 4 + r) * 40 + 16 + col] = f2bf(pB);
        }

        bf16x8 pf = *(const bf16x8*)&Pl[wave][col * 40 + quad * 8];

        #pragma unroll
        for (int ht = 0; ht < 16; ht++) {
            int h = ht * 16 + col;
            bf16x8 vf = *(const bf16x8*)&Vs[(size_t)h * 32 + ((quad ^ (h & 3)) * 8)];
            o[ht] = __builtin_amdgcn_mfma_f32_16x16x32_bf16(pf, vf, o[ht], 0, 0, 0);
        }
        __syncthreads();
    }

    #pragma unroll
    for (int r = 0; r < 4; r++) {
        #pragma unroll
        for (int m = 1; m < 16; m <<= 1)
            lsum[r] += __shfl_xor(lsum[r], m, 16);
        lsum[r] = 1.0f / lsum[r];
    }
    #pragma unroll
    for (int ht = 0; ht < 16; ht++) {
        #pragma unroll
        for (int r = 0; r < 4; r++) {
            int t = tw + quad * 4 + r;
            enc[(size_t)t * (NQ * HD) + n * HD + ht * 16 + col] = f2bf(o[ht][r] * lsum[r]);
        }
    }
}

extern "C" void kernel_launch(void* const* d_in, const int* in_sizes, int n_in,
                              void* d_out, int out_size, void* d_ws, size_t ws_size,
                              hipStream_t stream) {
    const float* x       = (const float*)d_in[0];
    const int*   spos    = (const int*)d_in[1];
    const float* w_q     = (const float*)d_in[3];
    const float* w_kv    = (const float*)d_in[4];
    const float* w_out   = (const float*)d_in[5];
    const float* q_scale = (const float*)d_in[6];
    const float* k_scale = (const float*)d_in[7];
    float* out = (float*)d_out;

    char* ws = (char*)d_ws;
    unsigned short* xb     = (unsigned short*)(ws + 0);          // 2048x3072 bf16 (dead after gemm1)
    unsigned short* vh     = (unsigned short*)(ws + 0);          // 8x2048x256 bf16 (reuses xb[0:8.4MB])
    float2*         trig   = (float2*)(ws + 8388608);            // 2048x128 float2 (reuses xb tail)
    unsigned short* wT     = (unsigned short*)(ws + 12582912);   // 8192x3072 bf16
    unsigned short* wToutb = (unsigned short*)(ws + 12582912);   // 3072x4096 bf16 (reuse)
    unsigned short* encb   = (unsigned short*)(ws + 37748736);   // 2048x4096 bf16 (reuse)
    unsigned short* qkv    = (unsigned short*)(ws + 62914560);   // 2048x8192 bf16
    unsigned short* qh     = (unsigned short*)(ws + 96468992);   // 16x2048x256 bf16
    unsigned short* kh     = (unsigned short*)(ws + 113246208);  // 8x2048x256 bf16
    unsigned short* vT     = (unsigned short*)(ws + 121634816);  // 8x256x2048 bf16

    k_convert<<<dim3((T_SEQ * D_MODEL / 4 + 255) / 256), dim3(256), 0, stream>>>(
        x, xb, T_SEQ * D_MODEL / 4);
    k_transpose_bf16<<<dim3(HD / 32, D_MODEL / 32, NQ), dim3(32, 8), 0, stream>>>(
        w_q, wT, D_MODEL, HD);
    k_transpose_bf16<<<dim3(HD / 32, D_MODEL / 32, 16), dim3(32, 8), 0, stream>>>(
        w_kv, wT + (size_t)4096 * D_MODEL, D_MODEL, HD);
    k_gemm1<<<dim3((T_SEQ / 256) * (QKV_COLS / 256)), dim3(512), 0, stream>>>(
        xb, wT, qkv, T_SEQ, QKV_COLS, D_MODEL);
    k_trig<<<dim3(T_SEQ), dim3(128), 0, stream>>>(spos, trig);
    k_transpose_bf16<<<dim3(D_MODEL / 32, 4096 / 32, 1), dim3(32, 8), 0, stream>>>(
        w_out, wToutb, 4096, D_MODEL);
    k_norm_rope<<<dim3(T_SEQ, 8), dim3(256), 0, stream>>>(
        qkv, trig, q_scale, k_scale, qh, kh, vh);
    k_transpose_v<<<dim3(HD / 32, T_SEQ / 32, NKV), dim3(32, 8), 0, stream>>>(vh, vT);
    k_attn<<<dim3(NKV, T_SEQ / 32), dim3(256), 0, stream>>>(qh, kh, vT, encb);
    k_gemm2<<<dim3((T_SEQ / 128) * (D_MODEL / 64)), dim3(256), 0, stream>>>(
        encb, wToutb, out, T_SEQ, D_MODEL, NQ * HD);
}

// Round 4
// 469.249 us; speedup vs baseline: 1.0323x; 1.0323x over previous
//
#include <hip/hip_runtime.h>
#include <math.h>

// Problem constants
#define T_SEQ 2048
#define D_MODEL 3072
#define NQ 16
#define NKV 8
#define HD 256
#define NHEADS_TOT 32
#define QKV_COLS 8192
#define SOFT_CAP 50.0f
#define WINDOW 1024
#define K_MASK -2.3819763e38f

typedef __attribute__((ext_vector_type(8))) short bf16x8;
typedef __attribute__((ext_vector_type(4))) float f32x4;

__device__ __forceinline__ unsigned short f2bf(float f) {
    union { float f; unsigned u; } v; v.f = f;
    unsigned r = (v.u + 0x7fff + ((v.u >> 16) & 1)) >> 16;
    return (unsigned short)r;
}
__device__ __forceinline__ float bf2f(unsigned short u) {
    union { unsigned u; float f; } v; v.u = ((unsigned)u) << 16;
    return v.f;
}

__device__ __forceinline__ void gl_lds16(const unsigned short* g, unsigned short* l) {
    __builtin_amdgcn_global_load_lds(
        (const __attribute__((address_space(1))) void*)g,
        (__attribute__((address_space(3))) void*)l, 16, 0, 0);
}

// ---------------- convert f32 -> bf16 (flat) ----------------
__global__ __launch_bounds__(256) void k_convert(const float* __restrict__ src,
                                                 unsigned short* __restrict__ dst, int n4) {
    int i = blockIdx.x * 256 + threadIdx.x;
    if (i >= n4) return;
    float4 v = ((const float4*)src)[i];
    ushort4 o;
    o.x = f2bf(v.x); o.y = f2bf(v.y); o.z = f2bf(v.z); o.w = f2bf(v.w);
    ((ushort4*)dst)[i] = o;
}

// ---------------- batched transpose+convert v2: (batch,R,C) f32 -> (batch,C,R) bf16 --------
// 64x64 tile, 256 threads.  Coalesced float4 reads (1 KB/wave-inst), convert in reg,
// scatter into transposed LDS tile, coalesced ushort4 writes (128 B per 16 lanes).
// Bit-identical to v1 (same f2bf; dst[c][r] = f2bf(src[r][c])).  Requires R%64==C%64==0.
__global__ __launch_bounds__(256) void k_transpose_bf16(const float* __restrict__ src,
                                                        unsigned short* __restrict__ dst,
                                                        int R, int C) {
    __shared__ unsigned short T[64][68];   // [src-col][src-row], pad 4 to break banks
    int b = blockIdx.z;
    src += (size_t)b * R * C;
    dst += (size_t)b * R * C;
    int c0 = blockIdx.x * 64, r0 = blockIdx.y * 64;
    int tid = threadIdx.x;
    int wv = tid >> 6, ln = tid & 63;
    int rsub = (wv << 2) + (ln >> 4);      // 0..15
    int cq = (ln & 15) << 2;               // 0,4,...,60
    #pragma unroll
    for (int p = 0; p < 4; p++) {
        int row = p * 16 + rsub;
        float4 v = *(const float4*)&src[(size_t)(r0 + row) * C + c0 + cq];
        T[cq + 0][row] = f2bf(v.x);
        T[cq + 1][row] = f2bf(v.y);
        T[cq + 2][row] = f2bf(v.z);
        T[cq + 3][row] = f2bf(v.w);
    }
    __syncthreads();
    #pragma unroll
    for (int q = 0; q < 4; q++) {
        int crow = q * 16 + rsub;          // output row = global col c0+crow
        ushort4 o = *(const ushort4*)&T[crow][cq];
        *(ushort4*)&dst[(size_t)(c0 + crow) * R + r0 + cq] = o;
    }
}

// ---------------- bf16 transpose: vh (8, T, H) -> vT (8, H, T) ----------------
__global__ __launch_bounds__(256) void k_transpose_v(const unsigned short* __restrict__ src,
                                                     unsigned short* __restrict__ dst) {
    __shared__ unsigned short tile[32][34];
    int kk = blockIdx.z;
    src += (size_t)kk * T_SEQ * HD;
    dst += (size_t)kk * HD * T_SEQ;
    int h0 = blockIdx.x * 32, t0 = blockIdx.y * 32;
    int tx = threadIdx.x, ty = threadIdx.y;   // 32 x 8
    #pragma unroll
    for (int i = ty; i < 32; i += 8)
        tile[i][tx] = src[(size_t)(t0 + i) * HD + h0 + tx];
    __syncthreads();
    #pragma unroll
    for (int i = ty; i < 32; i += 8)
        dst[(size_t)(h0 + i) * T_SEQ + t0 + tx] = tile[tx][i];
}

// ---------------- RoPE trig table: (T, 128) float2 {sin, cos} ----------------
__global__ __launch_bounds__(128) void k_trig(const int* __restrict__ spos,
                                              float2* __restrict__ tbl) {
    int t = blockIdx.x, hh = threadIdx.x;
    float fr = (float)hh * (1.0f / 128.0f);
    float ts = __expf(fr * 9.210340371976184f);   // 10000^fr
    float ang = (float)spos[t] / ts;
    float2 sc;
    sc.x = __sinf(ang);
    sc.y = __cosf(ang);
    tbl[(size_t)t * 128 + hh] = sc;
}

// ---------------- gemm1: C[M,N]=A*BT^T, 128x256 tile, BK=64, ONE round (512 blk @ 2/CU) ----------
// R4: reverted to the R0-proven structure (best measured ~95.8 µs).  Three schedule
// variants (1-phase drain-0, 8-phase, 8-phase pinned) all land 96-100 µs @ 42-45% MfmaUtil
// -> not intra-block-schedule-bound at this shape; stop tuning here.
// 4 waves, each computes 64x128 (acc 4x8 tiles = 128 AGPR). __launch_bounds__(256,2) caps regs at 256.
__global__ __launch_bounds__(256, 2) void k_gemm1(const unsigned short* __restrict__ A,
                                                  const unsigned short* __restrict__ BT,
                                                  unsigned short* __restrict__ C,
                                                  int M, int N, int Kd) {
    __shared__ unsigned short As[128 * 64];   // 16 KB
    __shared__ unsigned short Bs[256 * 64];   // 32 KB
    const int tid = threadIdx.x;
    const int wave = tid >> 6, lane = tid & 63;
    const int col = lane & 15, quad = lane >> 4;
    const int wr = wave & 1, wc = wave >> 1;

    int p = blockIdx.x;                 // 512 blocks
    int xcd = p & 7, q = p >> 3;        // q in [0,64)
    int i_t = q & 15, jj = q >> 4;      // i in [0,16), jj in [0,4)
    const int m0 = i_t * 128, n0 = (jj * 8 + xcd) * 256;

    const int lrow = lane >> 3, lchk = lane & 7;
    int soffA[4], soffB[8];
    #pragma unroll
    for (int s = 0; s < 4; s++) {
        int r = wave * 32 + s * 8 + lrow;
        soffA[s] = r * Kd + ((lchk ^ (r & 7)) * 8);
    }
    #pragma unroll
    for (int s = 0; s < 8; s++) {
        int r = wave * 64 + s * 8 + lrow;
        soffB[s] = r * Kd + ((lchk ^ (r & 7)) * 8);
    }
    const unsigned short* Ab = A + (size_t)m0 * Kd;
    const unsigned short* Bb = BT + (size_t)n0 * Kd;

    f32x4 acc[4][8];
    #pragma unroll
    for (int i = 0; i < 4; i++)
        #pragma unroll
        for (int j = 0; j < 8; j++)
            acc[i][j] = (f32x4){0.f, 0.f, 0.f, 0.f};

    const int sw = col & 7;

    for (int k0 = 0; k0 < Kd; k0 += 64) {
        #pragma unroll
        for (int s = 0; s < 4; s++)
            gl_lds16(Ab + soffA[s] + k0, &As[(wave * 32 + s * 8) * 64]);
        #pragma unroll
        for (int s = 0; s < 8; s++)
            gl_lds16(Bb + soffB[s] + k0, &Bs[(wave * 64 + s * 8) * 64]);
        __syncthreads();

        #pragma unroll
        for (int kk = 0; kk < 2; kk++) {
            const int chko = ((kk * 4 + quad) ^ sw) * 8;
            bf16x8 af[4];
            #pragma unroll
            for (int i = 0; i < 4; i++)
                af[i] = *(const bf16x8*)&As[(wr * 64 + i * 16 + col) * 64 + chko];
            #pragma unroll
            for (int j = 0; j < 8; j++) {
                bf16x8 bfr = *(const bf16x8*)&Bs[(wc * 128 + j * 16 + col) * 64 + chko];
                #pragma unroll
                for (int i = 0; i < 4; i++)
                    acc[i][j] = __builtin_amdgcn_mfma_f32_16x16x32_bf16(af[i], bfr, acc[i][j], 0, 0, 0);
            }
        }
        __syncthreads();
    }

    #pragma unroll
    for (int i = 0; i < 4; i++) {
        int row = m0 + wr * 64 + i * 16 + quad * 4;
        #pragma unroll
        for (int j = 0; j < 8; j++) {
            int c = n0 + wc * 128 + j * 16 + col;
            #pragma unroll
            for (int r = 0; r < 4; r++)
                C[(size_t)(row + r) * N + c] = f2bf(acc[i][j][r]);
        }
    }
}

// ---------------- gemm2: 128x64 tile, BK=128 (32 barriers), 768 blocks, f32 out ----------------
// Ascending k-order per element -> bit-identical to BK=64 version.
__global__ __launch_bounds__(256) void k_gemm2(const unsigned short* __restrict__ A,
                                               const unsigned short* __restrict__ BT,
                                               float* __restrict__ C,
                                               int M, int N, int Kd) {
    __shared__ unsigned short As[128 * 128];  // 32 KB
    __shared__ unsigned short Bs[64 * 128];   // 16 KB
    const int tid = threadIdx.x;
    const int wave = tid >> 6, lane = tid & 63;
    const int col = lane & 15, quad = lane >> 4;

    int p = blockIdx.x;                    // 768 blocks
    int xcd = p & 7, q = p >> 3;           // q in [0,96)
    int i_t = q % 16, jj = q / 16;         // jj in [0,6)
    const int m0 = i_t * 128, n0 = (jj * 8 + xcd) * 64;

    const int lrow = lane >> 4, lchk = lane & 15;
    int soffA[8], soffB[4];
    #pragma unroll
    for (int s = 0; s < 8; s++) {
        int r = wave * 32 + s * 4 + lrow;
        soffA[s] = r * Kd + ((lchk ^ (r & 7)) * 8);
    }
    #pragma unroll
    for (int s = 0; s < 4; s++) {
        int r = wave * 16 + s * 4 + lrow;
        soffB[s] = r * Kd + ((lchk ^ (r & 7)) * 8);
    }
    const unsigned short* Ab = A + (size_t)m0 * Kd;
    const unsigned short* Bb = BT + (size_t)n0 * Kd;

    f32x4 acc[2][4];
    #pragma unroll
    for (int i = 0; i < 2; i++)
        #pragma unroll
        for (int j = 0; j < 4; j++)
            acc[i][j] = (f32x4){0.f, 0.f, 0.f, 0.f};

    const int sw = col & 7;

    for (int k0 = 0; k0 < Kd; k0 += 128) {
        #pragma unroll
        for (int s = 0; s < 8; s++)
            gl_lds16(Ab + soffA[s] + k0, &As[(wave * 32 + s * 4) * 128]);
        #pragma unroll
        for (int s = 0; s < 4; s++)
            gl_lds16(Bb + soffB[s] + k0, &Bs[(wave * 16 + s * 4) * 128]);
        __syncthreads();

        #pragma unroll
        for (int kk = 0; kk < 4; kk++) {
            const int chko = ((kk * 4 + quad) ^ sw) * 8;
            bf16x8 af[2], bfr[4];
            #pragma unroll
            for (int i = 0; i < 2; i++)
                af[i] = *(const bf16x8*)&As[(wave * 32 + i * 16 + col) * 128 + chko];
            #pragma unroll
            for (int j = 0; j < 4; j++)
                bfr[j] = *(const bf16x8*)&Bs[(j * 16 + col) * 128 + chko];
            #pragma unroll
            for (int i = 0; i < 2; i++)
                #pragma unroll
                for (int j = 0; j < 4; j++)
                    acc[i][j] = __builtin_amdgcn_mfma_f32_16x16x32_bf16(af[i], bfr[j], acc[i][j], 0, 0, 0);
        }
        __syncthreads();
    }

    #pragma unroll
    for (int i = 0; i < 2; i++) {
        int row = m0 + wave * 32 + i * 16 + quad * 4;
        #pragma unroll
        for (int j = 0; j < 4; j++) {
            int c = n0 + j * 16 + col;
            #pragma unroll
            for (int r = 0; r < 4; r++)
                C[(size_t)(row + r) * N + c] = acc[i][j][r];
        }
    }
}

// ---------------- RMS-norm (+scale) + RoPE: 4 slots per block ----------------
__global__ __launch_bounds__(256) void k_norm_rope(const unsigned short* __restrict__ qkv,
                                                   const float2* __restrict__ trig,
                                                   const float* __restrict__ qscale,
                                                   const float* __restrict__ kscale,
                                                   unsigned short* __restrict__ qh,
                                                   unsigned short* __restrict__ kh,
                                                   unsigned short* __restrict__ vh) {
    const int t = blockIdx.x, y = blockIdx.y, h = threadIdx.x;
    __shared__ float wsum[4][4];
    __shared__ float ybuf[3][256];

    float val[4];
    #pragma unroll
    for (int g = 0; g < 4; g++)
        val[g] = bf2f(qkv[(size_t)t * QKV_COLS + (y + g * 8) * HD + h]);

    float ssg[4];
    #pragma unroll
    for (int g = 0; g < 4; g++) {
        float ss = val[g] * val[g];
        #pragma unroll
        for (int m = 1; m < 64; m <<= 1) ss += __shfl_xor(ss, m, 64);
        ssg[g] = ss;
    }
    if ((h & 63) == 0) {
        #pragma unroll
        for (int g = 0; g < 4; g++) wsum[g][h >> 6] = ssg[g];
    }
    __syncthreads();

    float2 sc = trig[(size_t)t * 128 + (h & 127)];
    float qs = 1.0f + qscale[h], ks = 1.0f + kscale[h];

    float yv[4];
    #pragma unroll
    for (int g = 0; g < 4; g++) {
        float tot = wsum[g][0] + wsum[g][1] + wsum[g][2] + wsum[g][3];
        float yy = val[g] * rsqrtf(tot * (1.0f / 256.0f) + 1e-6f);
        if (g < 2) yy *= qs;
        else if (g == 2) yy *= ks;
        yv[g] = yy;
        if (g < 3) ybuf[g][h] = yy;
    }
    __syncthreads();

    #pragma unroll
    for (int g = 0; g < 3; g++) {
        float other = ybuf[g][(h < 128) ? (h + 128) : (h - 128)];
        float outv = (h < 128) ? (yv[g] * sc.y - other * sc.x)
                               : (yv[g] * sc.y + other * sc.x);
        int slot = y + g * 8;
        if (slot < 16)
            qh[((size_t)slot * T_SEQ + t) * HD + h] = f2bf(outv);
        else
            kh[((size_t)(slot - 16) * T_SEQ + t) * HD + h] = f2bf(outv);
    }
    vh[((size_t)y * T_SEQ + t) * HD + h] = f2bf(yv[3]);
}

// ---------------- flash attention (32-s-tile, K/V double-buffered, counted prefetch) -----------
// R4: T3-minimum pipeline.  Stage tile j+1 into buf^1 BEFORE computing tile j (pinned with
// sched_barrier so the scheduler can't sink the stage), one __syncthreads per iter (its
// vmcnt(0)+lgkmcnt(0) drain now lands AFTER compute -> HBM latency hidden under QK/softmax/PV).
// Race-free: stages write the opposite buffer; end-of-iter barrier publishes across waves.
__global__ __launch_bounds__(256) void k_attn(const unsigned short* __restrict__ qh,
                                              const unsigned short* __restrict__ kh,
                                              const unsigned short* __restrict__ vT,
                                              unsigned short* __restrict__ enc) {
    __shared__ unsigned short Ks[2][32 * 256];
    __shared__ unsigned short Vs[2][256 * 32];
    __shared__ unsigned short Pl[4][16 * 40];

    const int tid = threadIdx.x;
    const int wave = tid >> 6, lane = tid & 63;
    const int col = lane & 15, quad = lane >> 4;
    const int kk = blockIdx.x;
    const int t0b = blockIdx.y * 32;
    const int headSel = wave & 1, rowSel = wave >> 1;
    const int n = kk * 2 + headSel;
    const int tw = t0b + rowSel * 16;

    const unsigned short* qp = qh + ((size_t)n * T_SEQ + tw) * HD;
    const unsigned short* kp = kh + (size_t)kk * T_SEQ * HD;
    const unsigned short* vp = vT + (size_t)kk * HD * T_SEQ;

    bf16x8 qf[8];
    #pragma unroll
    for (int c = 0; c < 8; c++)
        qf[c] = *(const bf16x8*)(qp + (size_t)col * HD + c * 32 + quad * 8);

    int preK[4], preV[4], ldsKo[4], ldsVo[4];
    #pragma unroll
    for (int i = 0; i < 4; i++) {
        int krow = 2 * (wave * 4 + i) + (lane >> 5);
        int kpos = lane & 31;
        preK[i] = krow * HD + ((kpos ^ (krow & 7)) * 8);
        ldsKo[i] = (wave * 4 + i) * 512;
        int vh2 = (wave * 4 + i) * 16 + (lane >> 2);
        int vpp = lane & 3;
        preV[i] = vh2 * T_SEQ + ((vpp ^ (vh2 & 3)) * 8);
        ldsVo[i] = (wave * 4 + i) * 512;
    }

    f32x4 o[16];
    #pragma unroll
    for (int h = 0; h < 16; h++) o[h] = (f32x4){0.f, 0.f, 0.f, 0.f};
    float lsum[4] = {0.f, 0.f, 0.f, 0.f};

    int s_begin = t0b - (WINDOW - 1);
    if (s_begin < 0) s_begin = 0;
    s_begin &= ~31;
    const int s_end = t0b + 32;

    // prologue: stage first tile into buf 0
    #pragma unroll
    for (int i = 0; i < 4; i++)
        gl_lds16(kp + (size_t)s_begin * HD + preK[i], &Ks[0][ldsKo[i]]);
    #pragma unroll
    for (int i = 0; i < 4; i++)
        gl_lds16(vp + (size_t)s_begin + preV[i], &Vs[0][ldsVo[i]]);
    __syncthreads();

    int nb = 0;
    for (int s0 = s_begin; s0 < s_end; s0 += 32) {
        // issue next tile's stage into the other buffer (overlaps with this compute)
        int s1 = s0 + 32;
        if (s1 < s_end) {
            #pragma unroll
            for (int i = 0; i < 4; i++)
                gl_lds16(kp + (size_t)s1 * HD + preK[i], &Ks[nb ^ 1][ldsKo[i]]);
            #pragma unroll
            for (int i = 0; i < 4; i++)
                gl_lds16(vp + (size_t)s1 + preV[i], &Vs[nb ^ 1][ldsVo[i]]);
        }
        __builtin_amdgcn_sched_barrier(0);   // keep stage issue ahead of compute

        f32x4 S0 = (f32x4){0.f, 0.f, 0.f, 0.f};
        f32x4 S1 = (f32x4){0.f, 0.f, 0.f, 0.f};
        #pragma unroll
        for (int c = 0; c < 8; c++) {
            bf16x8 kf = *(const bf16x8*)&Ks[nb][(size_t)col * HD + (((c * 4 + quad) ^ (col & 7)) * 8)];
            S0 = __builtin_amdgcn_mfma_f32_16x16x32_bf16(qf[c], kf, S0, 0, 0, 0);
        }
        #pragma unroll
        for (int c = 0; c < 8; c++) {
            bf16x8 kf = *(const bf16x8*)&Ks[nb][(size_t)(16 + col) * HD + (((c * 4 + quad) ^ (col & 7)) * 8)];
            S1 = __builtin_amdgcn_mfma_f32_16x16x32_bf16(qf[c], kf, S1, 0, 0, 0);
        }

        #pragma unroll
        for (int r = 0; r < 4; r++) {
            int t = tw + quad * 4 + r;
            int sA = s0 + col, sB = sA + 16;
            bool vA = (sA <= t) && (sA >= t - (WINDOW - 1));
            bool vB = (sB <= t) && (sB >= t - (WINDOW - 1));
            float eA = __expf(S0[r] * (2.0f / SOFT_CAP));
            float eB = __expf(S1[r] * (2.0f / SOFT_CAP));
            float rA = __builtin_amdgcn_rcpf(eA + 1.0f);
            float rB = __builtin_amdgcn_rcpf(eB + 1.0f);
            float pA = __expf(SOFT_CAP - 2.0f * SOFT_CAP * rA);
            float pB = __expf(SOFT_CAP - 2.0f * SOFT_CAP * rB);
            pA = vA ? pA : 0.0f;
            pB = vB ? pB : 0.0f;
            lsum[r] += pA + pB;
            Pl[wave][(quad * 4 + r) * 40 + col] = f2bf(pA);
            Pl[wave][(quad * 4 + r) * 40 + 16 + col] = f2bf(pB);
        }

        bf16x8 pf = *(const bf16x8*)&Pl[wave][col * 40 + quad * 8];

        #pragma unroll
        for (int ht = 0; ht < 16; ht++) {
            int h = ht * 16 + col;
            bf16x8 vf = *(const bf16x8*)&Vs[nb][(size_t)h * 32 + ((quad ^ (h & 3)) * 8)];
            o[ht] = __builtin_amdgcn_mfma_f32_16x16x32_bf16(pf, vf, o[ht], 0, 0, 0);
        }
        __syncthreads();   // drains vmcnt(0): next tile landed; publishes across waves
        nb ^= 1;
    }

    #pragma unroll
    for (int r = 0; r < 4; r++) {
        #pragma unroll
        for (int m = 1; m < 16; m <<= 1)
            lsum[r] += __shfl_xor(lsum[r], m, 16);
        lsum[r] = 1.0f / lsum[r];
    }
    #pragma unroll
    for (int ht = 0; ht < 16; ht++) {
        #pragma unroll
        for (int r = 0; r < 4; r++) {
            int t = tw + quad * 4 + r;
            enc[(size_t)t * (NQ * HD) + n * HD + ht * 16 + col] = f2bf(o[ht][r] * lsum[r]);
        }
    }
}

extern "C" void kernel_launch(void* const* d_in, const int* in_sizes, int n_in,
                              void* d_out, int out_size, void* d_ws, size_t ws_size,
                              hipStream_t stream) {
    const float* x       = (const float*)d_in[0];
    const int*   spos    = (const int*)d_in[1];
    const float* w_q     = (const float*)d_in[3];
    const float* w_kv    = (const float*)d_in[4];
    const float* w_out   = (const float*)d_in[5];
    const float* q_scale = (const float*)d_in[6];
    const float* k_scale = (const float*)d_in[7];
    float* out = (float*)d_out;

    char* ws = (char*)d_ws;
    unsigned short* xb     = (unsigned short*)(ws + 0);          // 2048x3072 bf16 (dead after gemm1)
    unsigned short* vh     = (unsigned short*)(ws + 0);          // 8x2048x256 bf16 (reuses xb[0:8.4MB])
    float2*         trig   = (float2*)(ws + 8388608);            // 2048x128 float2 (reuses xb tail)
    unsigned short* wT     = (unsigned short*)(ws + 12582912);   // 8192x3072 bf16
    unsigned short* wToutb = (unsigned short*)(ws + 12582912);   // 3072x4096 bf16 (reuse)
    unsigned short* encb   = (unsigned short*)(ws + 37748736);   // 2048x4096 bf16 (reuse)
    unsigned short* qkv    = (unsigned short*)(ws + 62914560);   // 2048x8192 bf16
    unsigned short* qh     = (unsigned short*)(ws + 96468992);   // 16x2048x256 bf16
    unsigned short* kh     = (unsigned short*)(ws + 113246208);  // 8x2048x256 bf16
    unsigned short* vT     = (unsigned short*)(ws + 121634816);  // 8x256x2048 bf16

    k_convert<<<dim3((T_SEQ * D_MODEL / 4 + 255) / 256), dim3(256), 0, stream>>>(
        x, xb, T_SEQ * D_MODEL / 4);
    k_transpose_bf16<<<dim3(HD / 64, D_MODEL / 64, NQ), dim3(256), 0, stream>>>(
        w_q, wT, D_MODEL, HD);
    k_transpose_bf16<<<dim3(HD / 64, D_MODEL / 64, 16), dim3(256), 0, stream>>>(
        w_kv, wT + (size_t)4096 * D_MODEL, D_MODEL, HD);
    k_gemm1<<<dim3((T_SEQ / 128) * (QKV_COLS / 256)), dim3(256), 0, stream>>>(
        xb, wT, qkv, T_SEQ, QKV_COLS, D_MODEL);
    k_trig<<<dim3(T_SEQ), dim3(128), 0, stream>>>(spos, trig);
    k_transpose_bf16<<<dim3(D_MODEL / 64, 4096 / 64, 1), dim3(256), 0, stream>>>(
        w_out, wToutb, 4096, D_MODEL);
    k_norm_rope<<<dim3(T_SEQ, 8), dim3(256), 0, stream>>>(
        qkv, trig, q_scale, k_scale, qh, kh, vh);
    k_transpose_v<<<dim3(HD / 32, T_SEQ / 32, NKV), dim3(32, 8), 0, stream>>>(vh, vT);
    k_attn<<<dim3(NKV, T_SEQ / 32), dim3(256), 0, stream>>>(qh, kh, vT, encb);
    k_gemm2<<<dim3((T_SEQ / 128) * (D_MODEL / 64)), dim3(256), 0, stream>>>(
        encb, wToutb, out, T_SEQ, D_MODEL, NQ * HD);
}